// Round 4
// baseline (556.561 us; speedup 1.0000x reference)
//
#include <hip/hip_runtime.h>
#include <math.h>

// ---------------------------------------------------------------------------
// GATv2 2-layer graph encoder, fp32 throughout.
// N=20000 nodes, E=640000 edges, D_IN=HC=128, H=4, C=32, D_OUT=64.
//
//  1. CSR build by dst (deg hist -> exclusive scan -> scatter), built once.
//  2. Per layer: xl = x@Wl+bl, xr = x@Wr+br  (fp32 LDS-tiled GEMM, K=128).
//  3. Fused per-dst-node kernel (1 wave = 1 node): gather xl[src], score via
//     16-lane shuffle reduce, online-softmax, self-loop merged, bias+ELU.
//  4. Final GEMM 128->64 into d_out.
// ---------------------------------------------------------------------------

// ---------------- CSR build ----------------

__global__ void hist_kernel(const int* __restrict__ ei, int E, int* __restrict__ deg) {
    int e = blockIdx.x * blockDim.x + threadIdx.x;
    if (e < E) atomicAdd(&deg[ei[E + e]], 1);   // dst = ei[E+e]
}

__global__ void exscan_kernel(const int* __restrict__ deg, int* __restrict__ rowptr,
                              int* __restrict__ cursor, int N) {
    __shared__ int buf[1024];
    __shared__ int carry_s;
    const int t = threadIdx.x;
    if (t == 0) carry_s = 0;
    __syncthreads();
    for (int base = 0; base < N; base += 1024) {
        int v = (base + t < N) ? deg[base + t] : 0;
        int x = v;
        buf[t] = x;
        __syncthreads();
        for (int off = 1; off < 1024; off <<= 1) {
            int y = (t >= off) ? buf[t - off] : 0;
            __syncthreads();
            x += y;
            buf[t] = x;
            __syncthreads();
        }
        int carry = carry_s;
        if (base + t < N) {
            int ex = carry + x - v;     // exclusive prefix
            rowptr[base + t] = ex;
            cursor[base + t] = ex;
        }
        __syncthreads();
        if (t == 1023) carry_s = carry + x;
        __syncthreads();
    }
    if (t == 0) rowptr[N] = carry_s;
}

__global__ void scatter_kernel(const int* __restrict__ ei, int E,
                               int* __restrict__ cursor, int* __restrict__ eidx) {
    int e = blockIdx.x * blockDim.x + threadIdx.x;
    if (e < E) {
        int d = ei[E + e];
        int pos = atomicAdd(&cursor[d], 1);
        eidx[pos] = e;
    }
}

// ---------------- fp32 GEMM, K fixed at 128 ----------------
// C[M,NCOL] = A[M,128] @ B[128,NCOL] + bias. Block: 256 thr, 32-row tile.
// B staged in LDS in 64-col panels (caps LDS at 48 KiB -> 3 blocks/CU).

template <int NCOL>
__global__ __launch_bounds__(256) void gemm128(const float* __restrict__ A,
                                               const float* __restrict__ B,
                                               const float* __restrict__ bias,
                                               float* __restrict__ C, int M) {
    constexpr int NP = (NCOL > 64) ? 64 : NCOL;  // panel width
    constexpr int CT = NP / 4;    // threads covering panel cols (float4 each)
    constexpr int RB = 256 / CT;  // distinct row-bases
    constexpr int RT = 32 / RB;   // rows per thread
    __shared__ float Bs[128 * NP];
    __shared__ float As[32 * 128];
    const int tid = threadIdx.x;

    const int row0 = blockIdx.x * 32;
    for (int i = tid * 4; i < 32 * 128; i += 1024) {
        int r = i >> 7, c = i & 127;
        int gr = row0 + r;
        float4 v = make_float4(0.f, 0.f, 0.f, 0.f);
        if (gr < M) v = *(const float4*)&A[(size_t)gr * 128 + c];
        *(float4*)&As[i] = v;
    }

    for (int panel = 0; panel < NCOL; panel += NP) {
        __syncthreads();
        for (int i = tid * 4; i < 128 * NP; i += 1024) {
            int k = i / NP, c = i % NP;
            *(float4*)&Bs[i] = *(const float4*)&B[(size_t)k * NCOL + panel + c];
        }
        __syncthreads();

        const int col4 = (tid % CT) * 4;
        const int rowbase = tid / CT;
        float acc[RT][4];
#pragma unroll
        for (int r = 0; r < RT; ++r)
            acc[r][0] = acc[r][1] = acc[r][2] = acc[r][3] = 0.f;

#pragma unroll 8
        for (int k = 0; k < 128; ++k) {
            float4 b4 = *(float4*)&Bs[k * NP + col4];
#pragma unroll
            for (int r = 0; r < RT; ++r) {
                float a = As[(rowbase + RB * r) * 128 + k];
                acc[r][0] = fmaf(a, b4.x, acc[r][0]);
                acc[r][1] = fmaf(a, b4.y, acc[r][1]);
                acc[r][2] = fmaf(a, b4.z, acc[r][2]);
                acc[r][3] = fmaf(a, b4.w, acc[r][3]);
            }
        }

        float4 bv = *(const float4*)&bias[panel + col4];
#pragma unroll
        for (int r = 0; r < RT; ++r) {
            int gr = row0 + rowbase + RB * r;
            if (gr < M) {
                float4 o = make_float4(acc[r][0] + bv.x, acc[r][1] + bv.y,
                                       acc[r][2] + bv.z, acc[r][3] + bv.w);
                *(float4*)&C[(size_t)gr * NCOL + panel + col4] = o;
            }
        }
    }
}

// ---------------- fused GATv2 edge pass: 1 wave per dst node ----------------
// lane l owns channels c = 2l, 2l+1; head = c/32 -> lanes [16h,16h+16).
// Online softmax over incoming edges + self loop; bias + ELU epilogue.

__global__ __launch_bounds__(256) void gat_fused(
    const float* __restrict__ xl, const float* __restrict__ xr,
    const int* __restrict__ ei, const float* __restrict__ ea,
    const float* __restrict__ We, const float* __restrict__ att,
    const float* __restrict__ bias, const int* __restrict__ rowptr,
    const int* __restrict__ eidx, float* __restrict__ out, int N) {
    const int gtid = blockIdx.x * blockDim.x + threadIdx.x;
    const int node = gtid >> 6;
    const int lane = threadIdx.x & 63;
    if (node >= N) return;
    const int c = lane * 2;

    const float2 xrv = *(const float2*)&xr[(size_t)node * 128 + c];
    const float2 wev = *(const float2*)&We[c];
    const float2 atv = *(const float2*)&att[c];

    float m = -INFINITY, den = 0.f, acc0 = 0.f, acc1 = 0.f;
    float ea_sum = 0.f;
    int cnt = 0;

    const int beg = rowptr[node], end = rowptr[node + 1];
    for (int p = beg; p < end; ++p) {
        const int e = eidx[p];
        const int s = ei[e];
        if (s == node) continue;  // PyG drops pre-existing self loops
        const float a = ea[e];
        ea_sum += a;
        ++cnt;
        const float2 xlv = *(const float2*)&xl[(size_t)s * 128 + c];
        float t0 = xlv.x + xrv.x + a * wev.x;
        float t1 = xlv.y + xrv.y + a * wev.y;
        t0 = t0 > 0.f ? t0 : 0.2f * t0;
        t1 = t1 > 0.f ? t1 : 0.2f * t1;
        float sc = t0 * atv.x + t1 * atv.y;
        sc += __shfl_xor(sc, 1);
        sc += __shfl_xor(sc, 2);
        sc += __shfl_xor(sc, 4);
        sc += __shfl_xor(sc, 8);   // per-head score, all 16 lanes of the head
        if (sc <= m) {
            const float pw = __expf(sc - m);
            den += pw;
            acc0 = fmaf(pw, xlv.x, acc0);
            acc1 = fmaf(pw, xlv.y, acc1);
        } else {
            const float r = __expf(m - sc);  // exp(-inf)=0 handles first edge
            den = fmaf(den, r, 1.f);
            acc0 = fmaf(acc0, r, xlv.x);
            acc1 = fmaf(acc1, r, xlv.y);
            m = sc;
        }
    }

    // self loop: edge_attr = mean of incoming non-self edge_attr (0 if none)
    {
        const float a = cnt > 0 ? ea_sum / (float)cnt : 0.f;
        const float2 xlv = *(const float2*)&xl[(size_t)node * 128 + c];
        float t0 = xlv.x + xrv.x + a * wev.x;
        float t1 = xlv.y + xrv.y + a * wev.y;
        t0 = t0 > 0.f ? t0 : 0.2f * t0;
        t1 = t1 > 0.f ? t1 : 0.2f * t1;
        float sc = t0 * atv.x + t1 * atv.y;
        sc += __shfl_xor(sc, 1);
        sc += __shfl_xor(sc, 2);
        sc += __shfl_xor(sc, 4);
        sc += __shfl_xor(sc, 8);
        if (sc <= m) {
            const float pw = __expf(sc - m);
            den += pw;
            acc0 = fmaf(pw, xlv.x, acc0);
            acc1 = fmaf(pw, xlv.y, acc1);
        } else {
            const float r = __expf(m - sc);
            den = fmaf(den, r, 1.f);
            acc0 = fmaf(acc0, r, xlv.x);
            acc1 = fmaf(acc1, r, xlv.y);
        }
    }

    const float inv = 1.f / den;
    float o0 = acc0 * inv + bias[c];
    float o1 = acc1 * inv + bias[c + 1];
    o0 = o0 > 0.f ? o0 : __expf(o0) - 1.f;   // ELU
    o1 = o1 > 0.f ? o1 : __expf(o1) - 1.f;
    *(float2*)&out[(size_t)node * 128 + c] = make_float2(o0, o1);
}

// ---------------------------------------------------------------------------

extern "C" void kernel_launch(void* const* d_in, const int* in_sizes, int n_in,
                              void* d_out, int out_size, void* d_ws, size_t ws_size,
                              hipStream_t stream) {
    const float* x    = (const float*)d_in[0];
    const int*   ei   = (const int*)d_in[1];   // [2,E]: src = ei[e], dst = ei[E+e]
    const float* ea   = (const float*)d_in[2];
    const float* Wl1  = (const float*)d_in[3];
    const float* bl1  = (const float*)d_in[4];
    const float* Wr1  = (const float*)d_in[5];
    const float* br1  = (const float*)d_in[6];
    const float* We1  = (const float*)d_in[7];
    const float* att1 = (const float*)d_in[8];
    const float* b1   = (const float*)d_in[9];
    const float* Wl2  = (const float*)d_in[10];
    const float* bl2  = (const float*)d_in[11];
    const float* Wr2  = (const float*)d_in[12];
    const float* br2  = (const float*)d_in[13];
    const float* We2  = (const float*)d_in[14];
    const float* att2 = (const float*)d_in[15];
    const float* b2   = (const float*)d_in[16];
    const float* Wo   = (const float*)d_in[17];
    const float* bo   = (const float*)d_in[18];
    float* out = (float*)d_out;

    const int N = in_sizes[0] / 128;
    const int E = in_sizes[1] / 2;

    char* base = (char*)d_ws;
    size_t off = 0;
    auto alloc = [&](size_t bytes) -> void* {
        void* p = base + off;
        off += (bytes + 255) & ~(size_t)255;
        return p;
    };
    float* xl   = (float*)alloc((size_t)N * 128 * 4);
    float* xr   = (float*)alloc((size_t)N * 128 * 4);
    float* h    = (float*)alloc((size_t)N * 128 * 4);
    int* deg    = (int*)alloc((size_t)N * 4);
    int* rowptr = (int*)alloc(((size_t)N + 1) * 4);
    int* cursor = (int*)alloc((size_t)N * 4);
    int* eidx   = (int*)alloc((size_t)E * 4);

    // --- CSR build (d_ws is re-poisoned each call: rebuild everything) ---
    hipMemsetAsync(deg, 0, (size_t)N * 4, stream);
    hist_kernel<<<(E + 255) / 256, 256, 0, stream>>>(ei, E, deg);
    exscan_kernel<<<1, 1024, 0, stream>>>(deg, rowptr, cursor, N);
    scatter_kernel<<<(E + 255) / 256, 256, 0, stream>>>(ei, E, cursor, eidx);

    const int gblk = (N + 31) / 32;
    const int fblk = (N + 3) / 4;   // 4 waves (nodes) per 256-thread block

    // --- layer 1 ---
    gemm128<128><<<gblk, 256, 0, stream>>>(x, Wl1, bl1, xl, N);
    gemm128<128><<<gblk, 256, 0, stream>>>(x, Wr1, br1, xr, N);
    gat_fused<<<fblk, 256, 0, stream>>>(xl, xr, ei, ea, We1, att1, b1, rowptr, eidx, h, N);

    // --- layer 2 ---
    gemm128<128><<<gblk, 256, 0, stream>>>(h, Wl2, bl2, xl, N);
    gemm128<128><<<gblk, 256, 0, stream>>>(h, Wr2, br2, xr, N);
    gat_fused<<<fblk, 256, 0, stream>>>(xl, xr, ei, ea, We2, att2, b2, rowptr, eidx, h, N);

    // --- output projection ---
    gemm128<64><<<gblk, 256, 0, stream>>>(h, Wo, bo, out, N);
}

// Round 5
// 385.239 us; speedup vs baseline: 1.4447x; 1.4447x over previous
//
#include <hip/hip_runtime.h>
#include <math.h>

// ---------------------------------------------------------------------------
// GATv2 2-layer graph encoder, fp32. N=20000, E=640000, HC=128, H=4, C=32.
// R4 changes vs baseline (driven by profile: gat_fused latency-bound 35% VALU,
// GEMMs ~48us each = 10x roofline):
//  - CSR stores src+ea directly (removes eidx->ei/ea dependent scattered loads)
//  - gat_fused: 8-wide edge batching (8 gathers in flight), branch-free online
//    softmax, readfirstlane'd row bounds; self-loop mean ea precomputed.
//  - GEMM: 32x64 tile, 2x4 register tile, padded-A LDS (conflict-free), k x4
//    unroll with float4 A reuse -> near-FMA-bound.
//  - Scan: chunked shuffle scan (2 barriers) instead of 400-barrier version.
// ---------------------------------------------------------------------------

#define CHUNK 32  // 1024 threads * 32 covers N up to 32768

// ---------------- CSR build ----------------

__global__ void hist_ea_kernel(const int* __restrict__ ei, const float* __restrict__ ea,
                               int E, int* __restrict__ deg, float* __restrict__ easum) {
    int e = blockIdx.x * blockDim.x + threadIdx.x;
    if (e < E) {
        int s = ei[e], d = ei[E + e];
        if (s != d) {                       // PyG drops pre-existing self loops
            atomicAdd(&deg[d], 1);
            atomicAdd(&easum[d], ea[e]);
        }
    }
}

__global__ __launch_bounds__(1024) void scan_kernel(const int* __restrict__ deg,
                                                    int* __restrict__ rowptr,
                                                    int* __restrict__ cursor, int N) {
    __shared__ int wsum[16];
    const int t = threadIdx.x;
    const int lane = t & 63, wid = t >> 6;
    const int base = t * CHUNK;
    int loc[CHUNK];
    int s = 0;
#pragma unroll
    for (int j = 0; j < CHUNK; ++j) {
        int idx = base + j;
        int v = (idx < N) ? deg[idx] : 0;
        loc[j] = s;                          // thread-local exclusive prefix
        s += v;
    }
    int sc = s;                              // wave inclusive scan of thread sums
#pragma unroll
    for (int off = 1; off < 64; off <<= 1) {
        int y = __shfl_up(sc, off);
        if (lane >= off) sc += y;
    }
    if (lane == 63) wsum[wid] = sc;
    __syncthreads();
    if (wid == 0) {
        int w = (lane < 16) ? wsum[lane] : 0;
#pragma unroll
        for (int off = 1; off < 16; off <<= 1) {
            int y = __shfl_up(w, off);
            if (lane >= off) w += y;
        }
        if (lane < 16) wsum[lane] = w;
    }
    __syncthreads();
    const int woff = (wid > 0) ? wsum[wid - 1] : 0;
    const int texcl = woff + sc - s;
#pragma unroll
    for (int j = 0; j < CHUNK; ++j) {
        int idx = base + j;
        if (idx < N) { rowptr[idx] = texcl + loc[j]; cursor[idx] = texcl + loc[j]; }
    }
    if (t == 1023) rowptr[N] = wsum[15];
}

__global__ void scatter_kernel(const int* __restrict__ ei, const float* __restrict__ ea,
                               int E, int* __restrict__ cursor,
                               int* __restrict__ csr_src, float* __restrict__ csr_ea) {
    int e = blockIdx.x * blockDim.x + threadIdx.x;
    if (e < E) {
        int s = ei[e], d = ei[E + e];
        if (s != d) {
            int pos = atomicAdd(&cursor[d], 1);
            csr_src[pos] = s;
            csr_ea[pos] = ea[e];
        }
    }
}

// ---------------- fp32 GEMM, K=128, 32x64 tile, 2x4 reg tile ----------------

#define FMA_ROW(accrow, aval, bvec)                                            \
    accrow[0] = fmaf(aval, bvec.x, accrow[0]);                                 \
    accrow[1] = fmaf(aval, bvec.y, accrow[1]);                                 \
    accrow[2] = fmaf(aval, bvec.z, accrow[2]);                                 \
    accrow[3] = fmaf(aval, bvec.w, accrow[3]);

__global__ __launch_bounds__(256) void gemm_tile(const float* __restrict__ A,
                                                 const float* __restrict__ B,
                                                 const float* __restrict__ bias,
                                                 float* __restrict__ C,
                                                 int M, int NCOL) {
    __shared__ float As[32 * 132];   // +4 pad: float4-aligned, 2-way banks max
    __shared__ float Bs[128 * 64];
    const int tid = threadIdx.x;
    const int tx = tid & 15, ty = tid >> 4;
    const int row0 = blockIdx.x * 32;
    const int col0 = blockIdx.y * 64;

#pragma unroll
    for (int it = 0; it < 4; ++it) {         // stage A: 32 rows x 128 k
        int i = tid * 4 + it * 1024;
        int r = i >> 7, k0 = i & 127;
        int gr = row0 + r;
        float4 v = make_float4(0.f, 0.f, 0.f, 0.f);
        if (gr < M) v = *(const float4*)&A[(size_t)gr * 128 + k0];
        *(float4*)&As[r * 132 + k0] = v;
    }
#pragma unroll
    for (int it = 0; it < 8; ++it) {         // stage B panel: 128 k x 64 cols
        int i = tid * 4 + it * 1024;
        int k = i >> 6, cc = i & 63;
        *(float4*)&Bs[k * 64 + cc] = *(const float4*)&B[(size_t)k * NCOL + col0 + cc];
    }
    __syncthreads();

    float acc[2][4] = {{0.f, 0.f, 0.f, 0.f}, {0.f, 0.f, 0.f, 0.f}};
    const float* As0 = &As[(2 * ty + 0) * 132];
    const float* As1 = &As[(2 * ty + 1) * 132];
    const int bcol = 4 * tx;
#pragma unroll 4
    for (int k0 = 0; k0 < 128; k0 += 4) {
        float4 a0 = *(const float4*)&As0[k0];
        float4 a1 = *(const float4*)&As1[k0];
        float4 b0 = *(const float4*)&Bs[(k0 + 0) * 64 + bcol];
        float4 b1 = *(const float4*)&Bs[(k0 + 1) * 64 + bcol];
        float4 b2 = *(const float4*)&Bs[(k0 + 2) * 64 + bcol];
        float4 b3 = *(const float4*)&Bs[(k0 + 3) * 64 + bcol];
        FMA_ROW(acc[0], a0.x, b0) FMA_ROW(acc[1], a1.x, b0)
        FMA_ROW(acc[0], a0.y, b1) FMA_ROW(acc[1], a1.y, b1)
        FMA_ROW(acc[0], a0.z, b2) FMA_ROW(acc[1], a1.z, b2)
        FMA_ROW(acc[0], a0.w, b3) FMA_ROW(acc[1], a1.w, b3)
    }

    float4 bv = *(const float4*)&bias[col0 + bcol];
#pragma unroll
    for (int rr = 0; rr < 2; ++rr) {
        int gr = row0 + 2 * ty + rr;
        if (gr < M) {
            float4 o = make_float4(acc[rr][0] + bv.x, acc[rr][1] + bv.y,
                                   acc[rr][2] + bv.z, acc[rr][3] + bv.w);
            *(float4*)&C[(size_t)gr * NCOL + col0 + bcol] = o;
        }
    }
}

// ---------------- fused GATv2 edge pass: 1 wave per dst node ----------------
// lane owns channels c=2l,2l+1; head h = c/32 -> 16-lane groups.
// Branch-free online softmax; 8-edge batches keep 8 gathers in flight.

__device__ __forceinline__ void gat_update(float xlx, float xly, float a,
                                           float xrx, float xry,
                                           float wex, float wey,
                                           float atx, float aty,
                                           float& m, float& den,
                                           float& acc0, float& acc1) {
    float t0 = fmaf(a, wex, xlx + xrx);
    float t1 = fmaf(a, wey, xly + xry);
    t0 = fmaxf(t0, 0.2f * t0);               // leaky_relu, branchless
    t1 = fmaxf(t1, 0.2f * t1);
    float sc = fmaf(t0, atx, t1 * aty);
    sc += __shfl_xor(sc, 1);
    sc += __shfl_xor(sc, 2);
    sc += __shfl_xor(sc, 4);
    sc += __shfl_xor(sc, 8);                 // 16-lane (per-head) sum
    float mn = fmaxf(m, sc);
    float rr = __expf(m - mn);               // m=-inf initial -> rr=0
    float pw = __expf(sc - mn);
    den = fmaf(den, rr, pw);
    acc0 = fmaf(acc0, rr, pw * xlx);
    acc1 = fmaf(acc1, rr, pw * xly);
    m = mn;
}

__global__ __launch_bounds__(256) void gat_fused(
    const float* __restrict__ xl, const float* __restrict__ xr,
    const int* __restrict__ csr_src, const float* __restrict__ csr_ea,
    const float* __restrict__ easum,
    const float* __restrict__ We, const float* __restrict__ att,
    const float* __restrict__ bias, const int* __restrict__ rowptr,
    float* __restrict__ out, int N) {
    const int node = (blockIdx.x * blockDim.x + threadIdx.x) >> 6;
    const int lane = threadIdx.x & 63;
    if (node >= N) return;
    const int c = lane * 2;

    const float2 xrv = *(const float2*)&xr[(size_t)node * 128 + c];
    const float2 wev = *(const float2*)&We[c];
    const float2 atv = *(const float2*)&att[c];

    float m = -INFINITY, den = 0.f, acc0 = 0.f, acc1 = 0.f;
    const int beg = __builtin_amdgcn_readfirstlane(rowptr[node]);
    const int end = __builtin_amdgcn_readfirstlane(rowptr[node + 1]);

    int p = beg;
    for (; p + 8 <= end; p += 8) {
        int sv[8]; float av[8]; float2 xv[8];
#pragma unroll
        for (int j = 0; j < 8; ++j) { sv[j] = csr_src[p + j]; av[j] = csr_ea[p + j]; }
#pragma unroll
        for (int j = 0; j < 8; ++j) xv[j] = *(const float2*)&xl[(size_t)sv[j] * 128 + c];
#pragma unroll
        for (int j = 0; j < 8; ++j)
            gat_update(xv[j].x, xv[j].y, av[j], xrv.x, xrv.y, wev.x, wev.y,
                       atv.x, atv.y, m, den, acc0, acc1);
    }
    if (p < end) {                            // tail (uniform branches: p,end uniform)
        int sv[8]; float av[8]; float2 xv[8];
#pragma unroll
        for (int j = 0; j < 8; ++j) {
            int q = (p + j < end) ? (p + j) : p;
            sv[j] = csr_src[q]; av[j] = csr_ea[q];
        }
#pragma unroll
        for (int j = 0; j < 8; ++j) xv[j] = *(const float2*)&xl[(size_t)sv[j] * 128 + c];
#pragma unroll
        for (int j = 0; j < 8; ++j)
            if (p + j < end)
                gat_update(xv[j].x, xv[j].y, av[j], xrv.x, xrv.y, wev.x, wev.y,
                           atv.x, atv.y, m, den, acc0, acc1);
    }

    // self loop: ea = mean of incoming non-self ea (0 if isolated)
    const int degn = end - beg;
    const float al = (degn > 0) ? easum[node] / (float)degn : 0.f;
    const float2 xself = *(const float2*)&xl[(size_t)node * 128 + c];
    gat_update(xself.x, xself.y, al, xrv.x, xrv.y, wev.x, wev.y,
               atv.x, atv.y, m, den, acc0, acc1);

    const float inv = 1.f / den;
    float o0 = acc0 * inv + bias[c];
    float o1 = acc1 * inv + bias[c + 1];
    o0 = o0 > 0.f ? o0 : __expf(o0) - 1.f;   // ELU
    o1 = o1 > 0.f ? o1 : __expf(o1) - 1.f;
    *(float2*)&out[(size_t)node * 128 + c] = make_float2(o0, o1);
}

// ---------------------------------------------------------------------------

extern "C" void kernel_launch(void* const* d_in, const int* in_sizes, int n_in,
                              void* d_out, int out_size, void* d_ws, size_t ws_size,
                              hipStream_t stream) {
    const float* x    = (const float*)d_in[0];
    const int*   ei   = (const int*)d_in[1];   // [2,E]: src = ei[e], dst = ei[E+e]
    const float* ea   = (const float*)d_in[2];
    const float* Wl1  = (const float*)d_in[3];
    const float* bl1  = (const float*)d_in[4];
    const float* Wr1  = (const float*)d_in[5];
    const float* br1  = (const float*)d_in[6];
    const float* We1  = (const float*)d_in[7];
    const float* att1 = (const float*)d_in[8];
    const float* b1   = (const float*)d_in[9];
    const float* Wl2  = (const float*)d_in[10];
    const float* bl2  = (const float*)d_in[11];
    const float* Wr2  = (const float*)d_in[12];
    const float* br2  = (const float*)d_in[13];
    const float* We2  = (const float*)d_in[14];
    const float* att2 = (const float*)d_in[15];
    const float* b2   = (const float*)d_in[16];
    const float* Wo   = (const float*)d_in[17];
    const float* bo   = (const float*)d_in[18];
    float* out = (float*)d_out;

    const int N = in_sizes[0] / 128;
    const int E = in_sizes[1] / 2;

    char* base = (char*)d_ws;
    size_t off = 0;
    auto alloc = [&](size_t bytes) -> void* {
        void* p = base + off;
        off += (bytes + 255) & ~(size_t)255;
        return p;
    };
    float* xl      = (float*)alloc((size_t)N * 128 * 4);
    float* xr      = (float*)alloc((size_t)N * 128 * 4);
    float* h       = (float*)alloc((size_t)N * 128 * 4);
    int*   deg     = (int*)alloc((size_t)N * 4);
    float* easum   = (float*)alloc((size_t)N * 4);
    int*   rowptr  = (int*)alloc(((size_t)N + 1) * 4);
    int*   cursor  = (int*)alloc((size_t)N * 4);
    int*   csr_src = (int*)alloc((size_t)E * 4);
    float* csr_ea  = (float*)alloc((size_t)E * 4);

    // --- CSR build (ws re-poisoned each call: rebuild) ---
    hipMemsetAsync(deg, 0, (size_t)N * 4, stream);
    hipMemsetAsync(easum, 0, (size_t)N * 4, stream);
    hist_ea_kernel<<<(E + 255) / 256, 256, 0, stream>>>(ei, ea, E, deg, easum);
    scan_kernel<<<1, 1024, 0, stream>>>(deg, rowptr, cursor, N);
    scatter_kernel<<<(E + 255) / 256, 256, 0, stream>>>(ei, ea, E, cursor, csr_src, csr_ea);

    const dim3 g2(( (unsigned)(N + 31) / 32 ), 2);
    const dim3 g1(( (unsigned)(N + 31) / 32 ), 1);
    const int fblk = (N + 3) / 4;

    // --- layer 1 ---
    gemm_tile<<<g2, 256, 0, stream>>>(x, Wl1, bl1, xl, N, 128);
    gemm_tile<<<g2, 256, 0, stream>>>(x, Wr1, br1, xr, N, 128);
    gat_fused<<<fblk, 256, 0, stream>>>(xl, xr, csr_src, csr_ea, easum,
                                        We1, att1, b1, rowptr, h, N);

    // --- layer 2 ---
    gemm_tile<<<g2, 256, 0, stream>>>(h, Wl2, bl2, xl, N, 128);
    gemm_tile<<<g2, 256, 0, stream>>>(h, Wr2, br2, xr, N, 128);
    gat_fused<<<fblk, 256, 0, stream>>>(xl, xr, csr_src, csr_ea, easum,
                                        We2, att2, b2, rowptr, h, N);

    // --- output projection (fully overwrites d_out: 625*32 = 20000 rows) ---
    gemm_tile<<<g1, 256, 0, stream>>>(h, Wo, bo, out, N, 64);
}

// Round 6
// 330.062 us; speedup vs baseline: 1.6862x; 1.1672x over previous
//
#include <hip/hip_runtime.h>
#include <math.h>

// ---------------------------------------------------------------------------
// GATv2 2-layer graph encoder, fp32. N=20000, E=640000, HC=128, H=4, C=32.
// R5 -> R6 changes (profile: hist_ea_kernel 61us = top dispatch; atomic
// line-writeback bound, WRITE_SIZE 39.6MB for 160KB of arrays):
//  - easum atomic removed: edge-attr sum accumulated in-register in gat_fused.
//  - rank-based CSR: hist keeps atomicAdd return value as rank[e]; scatter
//    becomes atomic-free (pos = rowptr[d] + rank[e]); cursor eliminated.
//  - CSR packed as int2{src, bitcast(ea)}: 1x8B store / 1x8B load per edge.
//  - gat_fused: 16-edge batches (16 gathers in flight).
// ---------------------------------------------------------------------------

#define CHUNK 32  // 1024 threads * 32 covers N up to 32768

// ---------------- CSR build ----------------

__global__ void hist_rank_kernel(const int* __restrict__ ei, int E,
                                 int* __restrict__ deg, int* __restrict__ rank) {
    int e = blockIdx.x * blockDim.x + threadIdx.x;
    if (e < E) {
        int s = ei[e], d = ei[E + e];
        if (s != d)                          // PyG drops pre-existing self loops
            rank[e] = atomicAdd(&deg[d], 1);
    }
}

__global__ __launch_bounds__(1024) void scan_kernel(const int* __restrict__ deg,
                                                    int* __restrict__ rowptr, int N) {
    __shared__ int wsum[16];
    const int t = threadIdx.x;
    const int lane = t & 63, wid = t >> 6;
    const int base = t * CHUNK;
    int loc[CHUNK];
    int s = 0;
#pragma unroll
    for (int j = 0; j < CHUNK; ++j) {
        int idx = base + j;
        int v = (idx < N) ? deg[idx] : 0;
        loc[j] = s;                          // thread-local exclusive prefix
        s += v;
    }
    int sc = s;                              // wave inclusive scan of thread sums
#pragma unroll
    for (int off = 1; off < 64; off <<= 1) {
        int y = __shfl_up(sc, off);
        if (lane >= off) sc += y;
    }
    if (lane == 63) wsum[wid] = sc;
    __syncthreads();
    if (wid == 0) {
        int w = (lane < 16) ? wsum[lane] : 0;
#pragma unroll
        for (int off = 1; off < 16; off <<= 1) {
            int y = __shfl_up(w, off);
            if (lane >= off) w += y;
        }
        if (lane < 16) wsum[lane] = w;
    }
    __syncthreads();
    const int woff = (wid > 0) ? wsum[wid - 1] : 0;
    const int texcl = woff + sc - s;
#pragma unroll
    for (int j = 0; j < CHUNK; ++j) {
        int idx = base + j;
        if (idx < N) rowptr[idx] = texcl + loc[j];
    }
    if (t == 1023) rowptr[N] = wsum[15];
}

__global__ void scatter_kernel(const int* __restrict__ ei, const float* __restrict__ ea,
                               const int* __restrict__ rank,
                               const int* __restrict__ rowptr,
                               int2* __restrict__ csr, int E) {
    int e = blockIdx.x * blockDim.x + threadIdx.x;
    if (e < E) {
        int s = ei[e], d = ei[E + e];
        if (s != d) {
            int pos = rowptr[d] + rank[e];   // no atomic: rank from hist pass
            csr[pos] = make_int2(s, __float_as_int(ea[e]));
        }
    }
}

// ---------------- fp32 GEMM, K=128, 32x64 tile, 2x4 reg tile ----------------

#define FMA_ROW(accrow, aval, bvec)                                            \
    accrow[0] = fmaf(aval, bvec.x, accrow[0]);                                 \
    accrow[1] = fmaf(aval, bvec.y, accrow[1]);                                 \
    accrow[2] = fmaf(aval, bvec.z, accrow[2]);                                 \
    accrow[3] = fmaf(aval, bvec.w, accrow[3]);

__global__ __launch_bounds__(256) void gemm_tile(const float* __restrict__ A,
                                                 const float* __restrict__ B,
                                                 const float* __restrict__ bias,
                                                 float* __restrict__ C,
                                                 int M, int NCOL) {
    __shared__ float As[32 * 132];   // +4 pad: float4-aligned, 2-way banks max
    __shared__ float Bs[128 * 64];
    const int tid = threadIdx.x;
    const int tx = tid & 15, ty = tid >> 4;
    const int row0 = blockIdx.x * 32;
    const int col0 = blockIdx.y * 64;

#pragma unroll
    for (int it = 0; it < 4; ++it) {         // stage A: 32 rows x 128 k
        int i = tid * 4 + it * 1024;
        int r = i >> 7, k0 = i & 127;
        int gr = row0 + r;
        float4 v = make_float4(0.f, 0.f, 0.f, 0.f);
        if (gr < M) v = *(const float4*)&A[(size_t)gr * 128 + k0];
        *(float4*)&As[r * 132 + k0] = v;
    }
#pragma unroll
    for (int it = 0; it < 8; ++it) {         // stage B panel: 128 k x 64 cols
        int i = tid * 4 + it * 1024;
        int k = i >> 6, cc = i & 63;
        *(float4*)&Bs[k * 64 + cc] = *(const float4*)&B[(size_t)k * NCOL + col0 + cc];
    }
    __syncthreads();

    float acc[2][4] = {{0.f, 0.f, 0.f, 0.f}, {0.f, 0.f, 0.f, 0.f}};
    const float* As0 = &As[(2 * ty + 0) * 132];
    const float* As1 = &As[(2 * ty + 1) * 132];
    const int bcol = 4 * tx;
#pragma unroll 4
    for (int k0 = 0; k0 < 128; k0 += 4) {
        float4 a0 = *(const float4*)&As0[k0];
        float4 a1 = *(const float4*)&As1[k0];
        float4 b0 = *(const float4*)&Bs[(k0 + 0) * 64 + bcol];
        float4 b1 = *(const float4*)&Bs[(k0 + 1) * 64 + bcol];
        float4 b2 = *(const float4*)&Bs[(k0 + 2) * 64 + bcol];
        float4 b3 = *(const float4*)&Bs[(k0 + 3) * 64 + bcol];
        FMA_ROW(acc[0], a0.x, b0) FMA_ROW(acc[1], a1.x, b0)
        FMA_ROW(acc[0], a0.y, b1) FMA_ROW(acc[1], a1.y, b1)
        FMA_ROW(acc[0], a0.z, b2) FMA_ROW(acc[1], a1.z, b2)
        FMA_ROW(acc[0], a0.w, b3) FMA_ROW(acc[1], a1.w, b3)
    }

    float4 bv = *(const float4*)&bias[col0 + bcol];
#pragma unroll
    for (int rr = 0; rr < 2; ++rr) {
        int gr = row0 + 2 * ty + rr;
        if (gr < M) {
            float4 o = make_float4(acc[rr][0] + bv.x, acc[rr][1] + bv.y,
                                   acc[rr][2] + bv.z, acc[rr][3] + bv.w);
            *(float4*)&C[(size_t)gr * NCOL + col0 + bcol] = o;
        }
    }
}

// ---------------- fused GATv2 edge pass: 1 wave per dst node ----------------
// lane owns channels c=2l,2l+1; head = c/32 -> 16-lane groups.
// Branch-free online softmax; 16-edge batches keep 16 gathers in flight.

__device__ __forceinline__ void gat_update(float xlx, float xly, float a,
                                           float xrx, float xry,
                                           float wex, float wey,
                                           float atx, float aty,
                                           float& m, float& den,
                                           float& acc0, float& acc1) {
    float t0 = fmaf(a, wex, xlx + xrx);
    float t1 = fmaf(a, wey, xly + xry);
    t0 = fmaxf(t0, 0.2f * t0);               // leaky_relu, branchless
    t1 = fmaxf(t1, 0.2f * t1);
    float sc = fmaf(t0, atx, t1 * aty);
    sc += __shfl_xor(sc, 1);
    sc += __shfl_xor(sc, 2);
    sc += __shfl_xor(sc, 4);
    sc += __shfl_xor(sc, 8);                 // 16-lane (per-head) sum
    float mn = fmaxf(m, sc);
    float rr = __expf(m - mn);               // m=-inf initial -> rr=0
    float pw = __expf(sc - mn);
    den = fmaf(den, rr, pw);
    acc0 = fmaf(acc0, rr, pw * xlx);
    acc1 = fmaf(acc1, rr, pw * xly);
    m = mn;
}

#define GAT_BATCH 16

__global__ __launch_bounds__(256) void gat_fused(
    const float* __restrict__ xl, const float* __restrict__ xr,
    const int2* __restrict__ csr,
    const float* __restrict__ We, const float* __restrict__ att,
    const float* __restrict__ bias, const int* __restrict__ rowptr,
    float* __restrict__ out, int N) {
    const int node = (blockIdx.x * blockDim.x + threadIdx.x) >> 6;
    const int lane = threadIdx.x & 63;
    if (node >= N) return;
    const int c = lane * 2;

    const float2 xrv = *(const float2*)&xr[(size_t)node * 128 + c];
    const float2 wev = *(const float2*)&We[c];
    const float2 atv = *(const float2*)&att[c];

    float m = -INFINITY, den = 0.f, acc0 = 0.f, acc1 = 0.f;
    float easum = 0.f;
    const int beg = __builtin_amdgcn_readfirstlane(rowptr[node]);
    const int end = __builtin_amdgcn_readfirstlane(rowptr[node + 1]);

    int p = beg;
    for (; p + GAT_BATCH <= end; p += GAT_BATCH) {
        int2 cv[GAT_BATCH]; float2 xv[GAT_BATCH];
#pragma unroll
        for (int j = 0; j < GAT_BATCH; ++j) cv[j] = csr[p + j];
#pragma unroll
        for (int j = 0; j < GAT_BATCH; ++j)
            xv[j] = *(const float2*)&xl[(size_t)cv[j].x * 128 + c];
#pragma unroll
        for (int j = 0; j < GAT_BATCH; ++j) {
            float a = __int_as_float(cv[j].y);
            easum += a;
            gat_update(xv[j].x, xv[j].y, a, xrv.x, xrv.y, wev.x, wev.y,
                       atv.x, atv.y, m, den, acc0, acc1);
        }
    }
    if (p < end) {                            // tail (p, end wave-uniform)
        int2 cv[GAT_BATCH]; float2 xv[GAT_BATCH];
#pragma unroll
        for (int j = 0; j < GAT_BATCH; ++j) {
            int q = (p + j < end) ? (p + j) : p;
            cv[j] = csr[q];
        }
#pragma unroll
        for (int j = 0; j < GAT_BATCH; ++j)
            xv[j] = *(const float2*)&xl[(size_t)cv[j].x * 128 + c];
#pragma unroll
        for (int j = 0; j < GAT_BATCH; ++j)
            if (p + j < end) {
                float a = __int_as_float(cv[j].y);
                easum += a;
                gat_update(xv[j].x, xv[j].y, a, xrv.x, xrv.y, wev.x, wev.y,
                           atv.x, atv.y, m, den, acc0, acc1);
            }
    }

    // self loop: ea = mean of incoming non-self ea (0 if isolated)
    const int degn = end - beg;
    const float al = (degn > 0) ? easum / (float)degn : 0.f;
    const float2 xself = *(const float2*)&xl[(size_t)node * 128 + c];
    gat_update(xself.x, xself.y, al, xrv.x, xrv.y, wev.x, wev.y,
               atv.x, atv.y, m, den, acc0, acc1);

    const float inv = 1.f / den;
    float o0 = acc0 * inv + bias[c];
    float o1 = acc1 * inv + bias[c + 1];
    o0 = o0 > 0.f ? o0 : __expf(o0) - 1.f;   // ELU
    o1 = o1 > 0.f ? o1 : __expf(o1) - 1.f;
    *(float2*)&out[(size_t)node * 128 + c] = make_float2(o0, o1);
}

// ---------------------------------------------------------------------------

extern "C" void kernel_launch(void* const* d_in, const int* in_sizes, int n_in,
                              void* d_out, int out_size, void* d_ws, size_t ws_size,
                              hipStream_t stream) {
    const float* x    = (const float*)d_in[0];
    const int*   ei   = (const int*)d_in[1];   // [2,E]: src = ei[e], dst = ei[E+e]
    const float* ea   = (const float*)d_in[2];
    const float* Wl1  = (const float*)d_in[3];
    const float* bl1  = (const float*)d_in[4];
    const float* Wr1  = (const float*)d_in[5];
    const float* br1  = (const float*)d_in[6];
    const float* We1  = (const float*)d_in[7];
    const float* att1 = (const float*)d_in[8];
    const float* b1   = (const float*)d_in[9];
    const float* Wl2  = (const float*)d_in[10];
    const float* bl2  = (const float*)d_in[11];
    const float* Wr2  = (const float*)d_in[12];
    const float* br2  = (const float*)d_in[13];
    const float* We2  = (const float*)d_in[14];
    const float* att2 = (const float*)d_in[15];
    const float* b2   = (const float*)d_in[16];
    const float* Wo   = (const float*)d_in[17];
    const float* bo   = (const float*)d_in[18];
    float* out = (float*)d_out;

    const int N = in_sizes[0] / 128;
    const int E = in_sizes[1] / 2;

    char* base = (char*)d_ws;
    size_t off = 0;
    auto alloc = [&](size_t bytes) -> void* {
        void* p = base + off;
        off += (bytes + 255) & ~(size_t)255;
        return p;
    };
    float* xl      = (float*)alloc((size_t)N * 128 * 4);
    float* xr      = (float*)alloc((size_t)N * 128 * 4);
    float* h       = (float*)alloc((size_t)N * 128 * 4);
    int*   deg     = (int*)alloc((size_t)N * 4);
    int*   rowptr  = (int*)alloc(((size_t)N + 1) * 4);
    int*   rank    = (int*)alloc((size_t)E * 4);
    int2*  csr     = (int2*)alloc((size_t)E * 8);

    // --- CSR build (ws re-poisoned each call: rebuild) ---
    hipMemsetAsync(deg, 0, (size_t)N * 4, stream);
    hist_rank_kernel<<<(E + 255) / 256, 256, 0, stream>>>(ei, E, deg, rank);
    scan_kernel<<<1, 1024, 0, stream>>>(deg, rowptr, N);
    scatter_kernel<<<(E + 255) / 256, 256, 0, stream>>>(ei, ea, rank, rowptr, csr, E);

    const dim3 g2(( (unsigned)(N + 31) / 32 ), 2);
    const dim3 g1(( (unsigned)(N + 31) / 32 ), 1);
    const int fblk = (N + 3) / 4;

    // --- layer 1 ---
    gemm_tile<<<g2, 256, 0, stream>>>(x, Wl1, bl1, xl, N, 128);
    gemm_tile<<<g2, 256, 0, stream>>>(x, Wr1, br1, xr, N, 128);
    gat_fused<<<fblk, 256, 0, stream>>>(xl, xr, csr, We1, att1, b1, rowptr, h, N);

    // --- layer 2 ---
    gemm_tile<<<g2, 256, 0, stream>>>(h, Wl2, bl2, xl, N, 128);
    gemm_tile<<<g2, 256, 0, stream>>>(h, Wr2, br2, xr, N, 128);
    gat_fused<<<fblk, 256, 0, stream>>>(xl, xr, csr, We2, att2, b2, rowptr, h, N);

    // --- output projection (fully overwrites d_out: 625*32 = 20000 rows) ---
    gemm_tile<<<g1, 256, 0, stream>>>(h, Wo, bo, out, N, 64);
}